// Round 1
// baseline (1270.680 us; speedup 1.0000x reference)
//
#include <hip/hip_runtime.h>

typedef float f4 __attribute__((ext_vector_type(4)));
typedef float f2 __attribute__((ext_vector_type(2)));

#define T_SEQ 512
#define LO2(v) __builtin_shufflevector(v, v, 0, 1)
#define HI2(v) __builtin_shufflevector(v, v, 2, 3)

__device__ __forceinline__ float sigmf(float v) {
    return 1.f / (1.f + __expf(-v));
}
__device__ __forceinline__ float tanhf_(float v) {
    v = fminf(fmaxf(v, -15.f), 15.f);
    float e = __expf(-2.f * v);
    return (1.f - e) / (1.f + e);
}

// matvec accumulate over one 96x32 (x-proj) + 96x32 (h-proj) pair, packed rows {l, l+16}
__device__ __forceinline__ void gru_matvec(
    const f4 (&Wg)[12][8][2][16], int wbase,
    const float (&sx)[16][36], const float (&sh)[16][36],
    int g, int l,
    f2& aIr, f2& aIz, f2& aIn, f2& aHr, f2& aHz, f2& aHn)
{
    #pragma unroll
    for (int k4 = 0; k4 < 8; ++k4) {
        f4 xv = *reinterpret_cast<const f4*>(&sx[g][4 * k4]);
        f4 hv = *reinterpret_cast<const f4*>(&sh[g][4 * k4]);
        #pragma unroll
        for (int ip = 0; ip < 2; ++ip) {
            f4 wir = Wg[wbase + 0][k4][ip][l];
            f4 wiz = Wg[wbase + 1][k4][ip][l];
            f4 win = Wg[wbase + 2][k4][ip][l];
            f4 whr = Wg[wbase + 3][k4][ip][l];
            f4 whz = Wg[wbase + 4][k4][ip][l];
            f4 whn = Wg[wbase + 5][k4][ip][l];
            float xs0 = xv[2 * ip], xs1 = xv[2 * ip + 1];
            float hs0 = hv[2 * ip], hs1 = hv[2 * ip + 1];
            f2 x0 = {xs0, xs0}, x1 = {xs1, xs1};
            f2 h0 = {hs0, hs0}, h1 = {hs1, hs1};
            aIr += LO2(wir) * x0; aIr += HI2(wir) * x1;
            aIz += LO2(wiz) * x0; aIz += HI2(wiz) * x1;
            aIn += LO2(win) * x0; aIn += HI2(win) * x1;
            aHr += LO2(whr) * h0; aHr += HI2(whr) * h1;
            aHz += LO2(whz) * h0; aHz += HI2(whz) * h1;
            aHn += LO2(whn) * h0; aHn += HI2(whn) * h1;
        }
    }
}

__device__ __forceinline__ f2 gru_gates(f2 aIr, f2 aIz, f2 aIn, f2 aHr, f2 aHz, f2 aHn, f2 hold) {
    f2 pr = aIr + aHr;
    f2 pz = aIz + aHz;
    f2 rg = {sigmf(pr[0]), sigmf(pr[1])};
    f2 zg = {sigmf(pz[0]), sigmf(pz[1])};
    f2 pn = aIn + rg * aHn;
    f2 ng = {tanhf_(pn[0]), tanhf_(pn[1])};
    return ng + zg * (hold - ng);   // (1-z)*n + z*h
}

__global__ __launch_bounds__(256)
void gru2_fused(const float* __restrict__ x,
                const float* __restrict__ W_ih0, const float* __restrict__ W_hh0,
                const float* __restrict__ b_ih0, const float* __restrict__ b_hh0,
                const float* __restrict__ W_ih1, const float* __restrict__ W_hh1,
                const float* __restrict__ b_ih1, const float* __restrict__ b_hh1,
                const float* __restrict__ W_proj, const float* __restrict__ b_proj,
                float* __restrict__ out)
{
    // WgP[gm][k4][ip][l] = {W[gt*32+l][k], W[gt*32+l+16][k], W[gt*32+l][k+1], W[gt*32+l+16][k+1]}
    // with gm = mat*3+gate (mat: ih0,hh0,ih1,hh1), k = k4*4 + 2*ip
    __shared__ f4 WgP[12][8][2][16];           // 48 KiB
    __shared__ float xb_s[16][36];             // per-group x_t (pad 36 for bank spread)
    __shared__ float h0_s[16][36];
    __shared__ float h1_s[16][36];
    __shared__ float Wp_s[16][32];

    const int tid = threadIdx.x;

    // ---- pack weights into LDS ----
    for (int it = 0; it < 12; ++it) {
        int idx = it * 256 + tid;              // [0, 3072)
        int gm = idx >> 8;
        int k4 = (idx >> 5) & 7;
        int ip = (idx >> 4) & 1;
        int l2 = idx & 15;
        int m = gm / 3;
        int gt = gm - 3 * m;
        const float* W = (m == 0) ? W_ih0 : (m == 1) ? W_hh0 : (m == 2) ? W_ih1 : W_hh1;
        int k = k4 * 4 + 2 * ip;
        int r0 = (gt * 32 + l2) * 32;
        int r1 = (gt * 32 + l2 + 16) * 32;
        f4 v;
        v[0] = W[r0 + k];
        v[1] = W[r1 + k];
        v[2] = W[r0 + k + 1];
        v[3] = W[r1 + k + 1];
        WgP[gm][k4][ip][l2] = v;
    }
    if (tid < 128) {
        reinterpret_cast<f4*>(&Wp_s[0][0])[tid] = reinterpret_cast<const f4*>(W_proj)[tid];
    }

    const int l = tid & 15;        // lane within group: owns hidden rows l and l+16
    const int g = tid >> 4;        // batch group within block (16 groups)
    const int b = blockIdx.x * 16 + g;

    // biases packed {row l, row l+16}
    f2 bI0r = {b_ih0[l], b_ih0[l + 16]};
    f2 bI0z = {b_ih0[32 + l], b_ih0[48 + l]};
    f2 bI0n = {b_ih0[64 + l], b_ih0[80 + l]};
    f2 bH0r = {b_hh0[l], b_hh0[l + 16]};
    f2 bH0z = {b_hh0[32 + l], b_hh0[48 + l]};
    f2 bH0n = {b_hh0[64 + l], b_hh0[80 + l]};
    f2 bI1r = {b_ih1[l], b_ih1[l + 16]};
    f2 bI1z = {b_ih1[32 + l], b_ih1[48 + l]};
    f2 bI1n = {b_ih1[64 + l], b_ih1[80 + l]};
    f2 bH1r = {b_hh1[l], b_hh1[l + 16]};
    f2 bH1z = {b_hh1[32 + l], b_hh1[48 + l]};
    f2 bH1n = {b_hh1[64 + l], b_hh1[80 + l]};

    h0_s[g][l] = 0.f; h0_s[g][l + 16] = 0.f;
    h1_s[g][l] = 0.f; h1_s[g][l + 16] = 0.f;

    __syncthreads();   // the only block-wide barrier

    const f2* xp = reinterpret_cast<const f2*>(x + (size_t)b * (T_SEQ * 32));
    f2 xr = xp[l];                         // prefetch t=0 (cols 2l, 2l+1)
    f2 h0own = {0.f, 0.f};
    f2 h1own = {0.f, 0.f};

    #pragma unroll 1
    for (int t = 0; t < T_SEQ; ++t) {
        // stage x_t into LDS; prefetch x_{t+1}
        *reinterpret_cast<f2*>(&xb_s[g][2 * l]) = xr;
        if (t + 1 < T_SEQ) xr = xp[(t + 1) * 16 + l];
        asm volatile("" ::: "memory");

        // ---- layer 0: inputs x_t, hidden h0 ----
        f2 aIr = bI0r, aIz = bI0z, aIn = bI0n;
        f2 aHr = bH0r, aHz = bH0z, aHn = bH0n;
        gru_matvec(WgP, 0, xb_s, h0_s, g, l, aIr, aIz, aIn, aHr, aHz, aHn);
        f2 h0new = gru_gates(aIr, aIz, aIn, aHr, aHz, aHn, h0own);
        h0own = h0new;
        h0_s[g][l] = h0new[0];
        h0_s[g][l + 16] = h0new[1];
        asm volatile("" ::: "memory");

        // ---- layer 1: inputs h0_new, hidden h1 ----
        aIr = bI1r; aIz = bI1z; aIn = bI1n;
        aHr = bH1r; aHz = bH1z; aHn = bH1n;
        gru_matvec(WgP, 6, h0_s, h1_s, g, l, aIr, aIz, aIn, aHr, aHz, aHn);
        f2 h1new = gru_gates(aIr, aIz, aIn, aHr, aHz, aHn, h1own);
        h1own = h1new;
        h1_s[g][l] = h1new[0];
        h1_s[g][l + 16] = h1new[1];
        asm volatile("" ::: "memory");
    }

    // ---- final projection: out[b][l] = b_proj[l] + dot(W_proj[l], h1) ----
    float acc = b_proj[l];
    #pragma unroll
    for (int k4 = 0; k4 < 8; ++k4) {
        f4 hv = *reinterpret_cast<const f4*>(&h1_s[g][4 * k4]);
        f4 wv = *reinterpret_cast<const f4*>(&Wp_s[l][4 * k4]);
        acc += wv[0] * hv[0] + wv[1] * hv[1] + wv[2] * hv[2] + wv[3] * hv[3];
    }
    out[b * 16 + l] = acc;
}

extern "C" void kernel_launch(void* const* d_in, const int* in_sizes, int n_in,
                              void* d_out, int out_size, void* d_ws, size_t ws_size,
                              hipStream_t stream) {
    const float* x      = (const float*)d_in[0];
    const float* W_ih0  = (const float*)d_in[1];
    const float* W_hh0  = (const float*)d_in[2];
    const float* b_ih0  = (const float*)d_in[3];
    const float* b_hh0  = (const float*)d_in[4];
    const float* W_ih1  = (const float*)d_in[5];
    const float* W_hh1  = (const float*)d_in[6];
    const float* b_ih1  = (const float*)d_in[7];
    const float* b_hh1  = (const float*)d_in[8];
    const float* W_proj = (const float*)d_in[9];
    const float* b_proj = (const float*)d_in[10];
    float* out = (float*)d_out;

    const int nb = in_sizes[0] / (T_SEQ * 32);   // 4096 batch elements
    const int grid = nb / 16;                    // 16 batches per 256-thread block

    hipLaunchKernelGGL(gru2_fused, dim3(grid), dim3(256), 0, stream,
                       x, W_ih0, W_hh0, b_ih0, b_hh0,
                       W_ih1, W_hh1, b_ih1, b_hh1, W_proj, b_proj, out);
}

// Round 2
// 1161.417 us; speedup vs baseline: 1.0941x; 1.0941x over previous
//
#include <hip/hip_runtime.h>

using bf16x8 = __attribute__((ext_vector_type(8))) short;
using f32x4  = __attribute__((ext_vector_type(4))) float;

#define T_SEQ 512
#define MFMA(A, B, C) __builtin_amdgcn_mfma_f32_16x16x32_bf16((A), (B), (C), 0, 0, 0)

__device__ __forceinline__ short f2bf(float f) {
    unsigned u = __float_as_uint(f);
    return (short)((u + 0x7fffu + ((u >> 16) & 1u)) >> 16);   // round-to-nearest-even
}
__device__ __forceinline__ float bf2f(short s) {
    return __uint_as_float(((unsigned)(unsigned short)s) << 16);
}

// Build hi/lo bf16 fragments from 8 f32 values (elements 0..3 from a, 4..7 from b).
__device__ __forceinline__ void split8(f32x4 a, f32x4 b, bf16x8& hi, bf16x8& lo) {
    #pragma unroll
    for (int j = 0; j < 4; ++j) {
        short h = f2bf(a[j]);
        hi[j] = h;
        lo[j] = f2bf(a[j] - bf2f(h));
        short g = f2bf(b[j]);
        hi[4 + j] = g;
        lo[4 + j] = f2bf(b[j] - bf2f(g));
    }
}

__device__ __forceinline__ void pack_frag(const float hf[8], bf16x8& hi, bf16x8& lo) {
    #pragma unroll
    for (int i = 0; i < 8; ++i) {
        short h = f2bf(hf[i]);
        hi[i] = h;
        lo[i] = f2bf(hf[i] - bf2f(h));
    }
}

__device__ __forceinline__ float sigmf(float v) { return 1.f / (1.f + __expf(-v)); }
__device__ __forceinline__ float tanhf_(float v) {
    v = fminf(fmaxf(v, -15.f), 15.f);
    float e = __expf(-2.f * v);
    return (1.f - e) / (1.f + e);
}

// Gate math for 8 hidden units per lane. arz: tiles 0..3 (r: 0,1  z: 2,3),
// axn/ahn: n-gate x-side and h-side (tiles 4,5). hf updated in place.
__device__ __forceinline__ void gru_gate8(const f32x4 arz[4], const f32x4 axn[2],
                                          const f32x4 ahn[2], float hf[8]) {
    #pragma unroll
    for (int s = 0; s < 2; ++s) {          // s=0: units 4q+j, s=1: units 16+4q+j
        #pragma unroll
        for (int j = 0; j < 4; ++j) {
            float r = sigmf(arz[s][j]);
            float z = sigmf(arz[2 + s][j]);
            float nn = tanhf_(axn[s][j] + r * ahn[s][j]);
            float& h = hf[4 * s + j];
            h = nn + z * (h - nn);
        }
    }
}

// One wave (64 threads) owns 16 batch elements. D = W(96x32) * h(32x16batches).
// Per-lane: batch = b0 + (lane&15); q = lane>>4; frag element positions 0..3 hold
// hidden units 4q+j, positions 4..7 hold 16+4q+j (consistent between A and B frags,
// so correct under any k-slot convention). D: col=lane&15 (batch), row=4q+reg.
__global__ __launch_bounds__(64, 1)
void gru2_mfma(const float* __restrict__ x,
               const float* __restrict__ W_ih0, const float* __restrict__ W_hh0,
               const float* __restrict__ b_ih0, const float* __restrict__ b_hh0,
               const float* __restrict__ W_ih1, const float* __restrict__ W_hh1,
               const float* __restrict__ b_ih1, const float* __restrict__ b_hh1,
               const float* __restrict__ W_proj, const float* __restrict__ b_proj,
               float* __restrict__ out)
{
    const int lane = threadIdx.x;
    const int r16  = lane & 15;
    const int q    = lane >> 4;
    const int b0   = blockIdx.x * 16;

    // ---- weight fragments, register-resident (hi/lo split) ----
    // m: 0=W_ih0, 1=W_hh0, 2=W_ih1, 3=W_hh1; t: M-tile (rows 16t..16t+15)
    bf16x8 Wh[4][6], Wl[4][6];
    {
        const float* Ws[4] = {W_ih0, W_hh0, W_ih1, W_hh1};
        #pragma unroll
        for (int m = 0; m < 4; ++m) {
            #pragma unroll
            for (int t = 0; t < 6; ++t) {
                const float* p = Ws[m] + (16 * t + r16) * 32 + 4 * q;
                split8(*(const f32x4*)p, *(const f32x4*)(p + 16), Wh[m][t], Wl[m][t]);
            }
        }
    }

    // ---- bias fragments (accumulator-layout: element reg -> row 16t+4q+reg) ----
    f32x4 brz0[4], brz1[4], bxn0[2], bhn0[2], bxn1[2], bhn1[2];
    #pragma unroll
    for (int t = 0; t < 4; ++t) {
        brz0[t] = *(const f32x4*)(b_ih0 + 16 * t + 4 * q) + *(const f32x4*)(b_hh0 + 16 * t + 4 * q);
        brz1[t] = *(const f32x4*)(b_ih1 + 16 * t + 4 * q) + *(const f32x4*)(b_hh1 + 16 * t + 4 * q);
    }
    #pragma unroll
    for (int t = 0; t < 2; ++t) {
        bxn0[t] = *(const f32x4*)(b_ih0 + 64 + 16 * t + 4 * q);
        bhn0[t] = *(const f32x4*)(b_hh0 + 64 + 16 * t + 4 * q);
        bxn1[t] = *(const f32x4*)(b_ih1 + 64 + 16 * t + 4 * q);
        bhn1[t] = *(const f32x4*)(b_hh1 + 64 + 16 * t + 4 * q);
    }

    // ---- state ----
    bf16x8 h0h = {}, h0l = {}, h1h = {}, h1l = {};
    float h0f[8] = {}, h1f[8] = {};

    // x: lane reads units {4q+j, 16+4q+j} of batch b0+r16 (two 16B loads per step)
    const float* xp = x + (size_t)(b0 + r16) * (T_SEQ * 32) + 4 * q;
    f32x4 xA = *(const f32x4*)(xp);
    f32x4 xB = *(const f32x4*)(xp + 16);

    #pragma unroll 1
    for (int t = 0; t < T_SEQ; ++t) {
        bf16x8 xh, xl;
        split8(xA, xB, xh, xl);
        if (t + 1 < T_SEQ) {               // prefetch next step's x
            xA = *(const f32x4*)(xp + (t + 1) * 32);
            xB = *(const f32x4*)(xp + (t + 1) * 32 + 16);
        }

        // ---------- layer 0 ----------
        f32x4 arz[4], axn[2], ahn[2];
        #pragma unroll
        for (int i = 0; i < 4; ++i) arz[i] = brz0[i];
        axn[0] = bxn0[0]; axn[1] = bxn0[1];
        ahn[0] = bhn0[0]; ahn[1] = bhn0[1];

        #pragma unroll
        for (int tt = 0; tt < 4; ++tt) {   // r,z tiles: x-side then h-side
            arz[tt] = MFMA(Wh[0][tt], xh, arz[tt]);
            arz[tt] = MFMA(Wh[0][tt], xl, arz[tt]);
            arz[tt] = MFMA(Wl[0][tt], xh, arz[tt]);
            arz[tt] = MFMA(Wh[1][tt], h0h, arz[tt]);
            arz[tt] = MFMA(Wh[1][tt], h0l, arz[tt]);
            arz[tt] = MFMA(Wl[1][tt], h0h, arz[tt]);
        }
        #pragma unroll
        for (int tt = 0; tt < 2; ++tt) {   // n tiles: keep x-side and h-side separate
            axn[tt] = MFMA(Wh[0][4 + tt], xh, axn[tt]);
            axn[tt] = MFMA(Wh[0][4 + tt], xl, axn[tt]);
            axn[tt] = MFMA(Wl[0][4 + tt], xh, axn[tt]);
            ahn[tt] = MFMA(Wh[1][4 + tt], h0h, ahn[tt]);
            ahn[tt] = MFMA(Wh[1][4 + tt], h0l, ahn[tt]);
            ahn[tt] = MFMA(Wl[1][4 + tt], h0h, ahn[tt]);
        }
        gru_gate8(arz, axn, ahn, h0f);
        pack_frag(h0f, h0h, h0l);

        // ---------- layer 1 (input = new h0) ----------
        f32x4 arz1[4], axn1[2], ahn1[2];
        #pragma unroll
        for (int i = 0; i < 4; ++i) arz1[i] = brz1[i];
        axn1[0] = bxn1[0]; axn1[1] = bxn1[1];
        ahn1[0] = bhn1[0]; ahn1[1] = bhn1[1];

        #pragma unroll
        for (int tt = 0; tt < 4; ++tt) {
            arz1[tt] = MFMA(Wh[2][tt], h0h, arz1[tt]);
            arz1[tt] = MFMA(Wh[2][tt], h0l, arz1[tt]);
            arz1[tt] = MFMA(Wl[2][tt], h0h, arz1[tt]);
            arz1[tt] = MFMA(Wh[3][tt], h1h, arz1[tt]);
            arz1[tt] = MFMA(Wh[3][tt], h1l, arz1[tt]);
            arz1[tt] = MFMA(Wl[3][tt], h1h, arz1[tt]);
        }
        #pragma unroll
        for (int tt = 0; tt < 2; ++tt) {
            axn1[tt] = MFMA(Wh[2][4 + tt], h0h, axn1[tt]);
            axn1[tt] = MFMA(Wh[2][4 + tt], h0l, axn1[tt]);
            axn1[tt] = MFMA(Wl[2][4 + tt], h0h, axn1[tt]);
            ahn1[tt] = MFMA(Wh[3][4 + tt], h1h, ahn1[tt]);
            ahn1[tt] = MFMA(Wh[3][4 + tt], h1l, ahn1[tt]);
            ahn1[tt] = MFMA(Wl[3][4 + tt], h1h, ahn1[tt]);
        }
        gru_gate8(arz1, axn1, ahn1, h1f);
        pack_frag(h1f, h1h, h1l);
    }

    // ---- projection: out[b][o] = b_proj[o] + sum_u W_proj[o][u] * h1[u] ----
    const float* pp = W_proj + r16 * 32 + 4 * q;
    bf16x8 Wph, Wpl;
    split8(*(const f32x4*)pp, *(const f32x4*)(pp + 16), Wph, Wpl);
    f32x4 accp = *(const f32x4*)(b_proj + 4 * q);   // element reg -> output row 4q+reg
    accp = MFMA(Wph, h1h, accp);
    accp = MFMA(Wph, h1l, accp);
    accp = MFMA(Wpl, h1h, accp);

    #pragma unroll
    for (int rg = 0; rg < 4; ++rg)
        out[(b0 + r16) * 16 + 4 * q + rg] = accp[rg];
}

extern "C" void kernel_launch(void* const* d_in, const int* in_sizes, int n_in,
                              void* d_out, int out_size, void* d_ws, size_t ws_size,
                              hipStream_t stream) {
    const float* x      = (const float*)d_in[0];
    const float* W_ih0  = (const float*)d_in[1];
    const float* W_hh0  = (const float*)d_in[2];
    const float* b_ih0  = (const float*)d_in[3];
    const float* b_hh0  = (const float*)d_in[4];
    const float* W_ih1  = (const float*)d_in[5];
    const float* W_hh1  = (const float*)d_in[6];
    const float* b_ih1  = (const float*)d_in[7];
    const float* b_hh1  = (const float*)d_in[8];
    const float* W_proj = (const float*)d_in[9];
    const float* b_proj = (const float*)d_in[10];
    float* out = (float*)d_out;

    const int nb   = in_sizes[0] / (T_SEQ * 32);   // 4096 batch elements
    const int grid = nb / 16;                      // 16 batches per 1-wave block

    hipLaunchKernelGGL(gru2_mfma, dim3(grid), dim3(64), 0, stream,
                       x, W_ih0, W_hh0, b_ih0, b_hh0,
                       W_ih1, W_hh1, b_ih1, b_hh1, W_proj, b_proj, out);
}